// Round 4
// baseline (54.441 us; speedup 1.0000x reference)
//
#include <hip/hip_runtime.h>

#define HH 128
#define WW 128
#define KK 64
#define SS 16
#define S3 (SS * SS * SS)
#define VOLRADIUS 256.0f
#define CULL_EPS 1e-3f
#define GPIX 4

// ---- DPP inclusive scan (gfx9 pattern: row_shr 1/2/4/8 + row_bcast 15/31) ----
template <int CTRL, int RM>
__device__ __forceinline__ float dpp_add(float x) {
    int y = __builtin_amdgcn_update_dpp(0, __float_as_int(x), CTRL, RM, 0xF, false);
    return x + __int_as_float(y);
}
__device__ __forceinline__ float wave_incl_scan(float x) {
    x = dpp_add<0x111, 0xF>(x);   // row_shr:1
    x = dpp_add<0x112, 0xF>(x);   // row_shr:2
    x = dpp_add<0x114, 0xF>(x);   // row_shr:4
    x = dpp_add<0x118, 0xF>(x);   // row_shr:8
    x = dpp_add<0x142, 0xA>(x);   // row_bcast:15 -> rows 1,3
    x = dpp_add<0x143, 0xC>(x);   // row_bcast:31 -> rows 2,3
    return x;                     // lane i = sum(lanes 0..i); lane 63 = total
}

#define LERP4(a, b, f) make_float4(a.x*(1.f-(f)) + b.x*(f), a.y*(1.f-(f)) + b.y*(f), \
                                   a.z*(1.f-(f)) + b.z*(f), a.w*(1.f-(f)) + b.w*(f))

#define GATHER8(C, base) {                                  \
    C[0] = (base)[0];            C[1] = (base)[1];          \
    C[2] = (base)[SS];           C[3] = (base)[SS+1];       \
    C[4] = (base)[SS*SS];        C[5] = (base)[SS*SS+1];    \
    C[6] = (base)[SS*SS+SS];     C[7] = (base)[SS*SS+SS+1]; }

#define TRILERP_ACC(p, C) {                                 \
    float4 c00 = LERP4(C[0], C[1], ffx[p]);                 \
    float4 c01 = LERP4(C[2], C[3], ffx[p]);                 \
    float4 c10 = LERP4(C[4], C[5], ffx[p]);                 \
    float4 c11 = LERP4(C[6], C[7], ffx[p]);                 \
    float4 e0  = LERP4(c00, c01, ffy[p]);                   \
    float4 e1  = LERP4(c10, c11, ffy[p]);                   \
    float fz = ffz[p], w = wv[p];                           \
    sv0[p] += (e0.x*(1.f-fz) + e1.x*fz) * w;                \
    sv1[p] += (e0.y*(1.f-fz) + e1.y*fz) * w;                \
    sv2[p] += (e0.z*(1.f-fz) + e1.z*fz) * w;                \
    sv3[p] += (e0.w*(1.f-fz) + e1.w*fz) * w; }

// template [K,4,S,S,S] -> ws [K,S,S,S,4] so each trilinear corner is one float4
__global__ __launch_bounds__(256) void transpose_tpl(const float* __restrict__ tpl,
                                                     float4* __restrict__ tw) {
    int i = blockIdx.x * blockDim.x + threadIdx.x;      // 0 .. K*S3
    if (i >= KK * S3) return;
    int k = i >> 12, v = i & (S3 - 1);
    const float* src = tpl + ((size_t)k * 4 * S3) + v;
    tw[i] = make_float4(src[0], src[S3], src[2 * S3], src[3 * S3]);
}

template <bool TR>
__global__ __launch_bounds__(256) void raymarch_kernel(
    const float* __restrict__ viewpos,   // [3]
    const float* __restrict__ raydir,    // [H,W,3]
    const float* __restrict__ tpl,       // [K,4,S,S,S]
    const float* __restrict__ primpos,   // [K,3]
    const float* __restrict__ primrot,   // [K,3,3]
    const float* __restrict__ primscale, // [K,3]
    const float* __restrict__ dtp,       // [1]
    const float4* __restrict__ tw,       // [K,S3] rgba (if TR)
    float* __restrict__ out)
{
    const int lane = threadIdx.x & 63;
    const int wid  = (int)((blockIdx.x * blockDim.x + threadIdx.x) >> 6);
    if (wid >= (HH * WW) / GPIX) return;
    // 2x2 pixel quad per wave (tighter prim coherence than a 4-wide strip)
    const int qh = wid / (WW / 2), qw = wid % (WW / 2);
    const int p00 = (2 * qh) * WW + 2 * qw;
    int pixidx[GPIX] = { p00, p00 + 1, p00 + WW, p00 + WW + 1 };

    const float vx = viewpos[0] / VOLRADIUS;
    const float vy = viewpos[1] / VOLRADIUS;
    const float vz = viewpos[2] / VOLRADIUS;
    const float dtn = dtp[0] / VOLRADIUS;

    // lane = prim k: params for the cull phase
    const float px = primpos[lane*3+0], py = primpos[lane*3+1], pz = primpos[lane*3+2];
    const float r00 = primrot[lane*9+0], r01 = primrot[lane*9+1], r02 = primrot[lane*9+2];
    const float r10 = primrot[lane*9+3], r11 = primrot[lane*9+4], r12 = primrot[lane*9+5];
    const float r20 = primrot[lane*9+6], r21 = primrot[lane*9+7], r22 = primrot[lane*9+8];
    const float sx = primscale[lane*3+0], sy = primscale[lane*3+1], sz = primscale[lane*3+2];
    // origin in local prim space (ray-independent)
    const float bx = ((vx-px)*r00 + (vy-py)*r10 + (vz-pz)*r20) * sx;
    const float by = ((vx-px)*r01 + (vy-py)*r11 + (vz-pz)*r21) * sy;
    const float bz = ((vx-px)*r02 + (vy-py)*r12 + (vz-pz)*r22) * sz;

    float rx[GPIX], ry[GPIX], rz[GPIX], tmn[GPIX], tmx[GPIX];
    float posx[GPIX], posy[GPIX], posz[GPIX];
    bool tvalid[GPIX];
    unsigned long long mask = 0ull;

#pragma unroll
    for (int p = 0; p < GPIX; ++p) {
        const int pix = pixidx[p];
        const float Rx = raydir[pix*3+0], Ry = raydir[pix*3+1], Rz = raydir[pix*3+2];
        rx[p] = Rx; ry[p] = Ry; rz[p] = Rz;
        // slab vs [-1,1]^3, exactly as reference
        float t1x = (-1.f-vx)/Rx, t2x = (1.f-vx)/Rx;
        float t1y = (-1.f-vy)/Ry, t2y = (1.f-vy)/Ry;
        float t1z = (-1.f-vz)/Rz, t2z = (1.f-vz)/Rz;
        float tmin = fmaxf(fminf(t1x,t2x), fmaxf(fminf(t1y,t2y), fminf(t1z,t2z)));
        float tmax = fminf(fmaxf(t1x,t2x), fminf(fmaxf(t1y,t2y), fmaxf(t1z,t2z)));
        bool inter = tmin < tmax;
        float tmin_ = inter ? tmin : 0.f;
        float tmax_ = inter ? tmax : 0.f;
        tmn[p] = tmin_; tmx[p] = tmax_;
        float t0 = fmaxf(tmin_, 0.f);
        float t = t0 + (float)lane * dtn;          // lane = step index
        tvalid[p] = t < tmax_;
        posx[p] = vx + Rx*t; posy[p] = vy + Ry*t; posz[p] = vz + Rz*t;

        // conservative ray-vs-OBB cull in local space (widened by CULL_EPS)
        float dxl = (Rx*r00 + Ry*r10 + Rz*r20) * sx;
        float dyl = (Rx*r01 + Ry*r11 + Rz*r21) * sy;
        float dzl = (Rx*r02 + Ry*r12 + Rz*r22) * sz;
        float tend = fminf(tmax_, t0 + 63.f*dtn);
        float te = t0, tx = tend;
        float bb[3] = {bx, by, bz};
        float dd[3] = {dxl, dyl, dzl};
#pragma unroll
        for (int j = 0; j < 3; ++j) {
            float ta, tb2;
            if (fabsf(dd[j]) > 1e-12f) {
                float inv = 1.f / dd[j];
                ta  = (-1.f - CULL_EPS - bb[j]) * inv;
                tb2 = ( 1.f + CULL_EPS - bb[j]) * inv;
            } else {
                bool ok = fabsf(bb[j]) <= 1.f + CULL_EPS;
                ta  = ok ? -3e38f :  3e38f;
                tb2 = ok ?  3e38f : -3e38f;
            }
            te = fmaxf(te, fminf(ta, tb2));
            tx = fminf(tx, fmaxf(ta, tb2));
        }
        mask |= __ballot(te <= tx);
    }

    float sv0[GPIX] = {}, sv1[GPIX] = {}, sv2[GPIX] = {}, sv3[GPIX] = {};

    while (mask) {
        int kf = __ffsll(mask) - 1;
        mask &= mask - 1;
        const int ku = __builtin_amdgcn_readfirstlane(kf);   // uniform -> s_loads
        const float qpx = primpos[ku*3+0], qpy = primpos[ku*3+1], qpz = primpos[ku*3+2];
        const float q00 = primrot[ku*9+0], q01 = primrot[ku*9+1], q02 = primrot[ku*9+2];
        const float q10 = primrot[ku*9+3], q11 = primrot[ku*9+4], q12 = primrot[ku*9+5];
        const float q20 = primrot[ku*9+6], q21 = primrot[ku*9+7], q22 = primrot[ku*9+8];
        const float qsx = primscale[ku*3+0], qsy = primscale[ku*3+1], qsz = primscale[ku*3+2];

        // branchless: reference gathers with clamped idx for every (point,prim)
        // and multiplies by `inside` -- identical math, no exec-mask churn.
        float ffx[GPIX], ffy[GPIX], ffz[GPIX], wv[GPIX];
        int idx[GPIX];
#pragma unroll
        for (int p = 0; p < GPIX; ++p) {
            float xmx = posx[p]-qpx, xmy = posy[p]-qpy, xmz = posz[p]-qpz;
            float y0 = (xmx*q00 + xmy*q10 + xmz*q20) * qsx;
            float y1 = (xmx*q01 + xmy*q11 + xmz*q21) * qsy;
            float y2 = (xmx*q02 + xmy*q12 + xmz*q22) * qsz;
            bool samp = tvalid[p] && fabsf(y0) < 1.f && fabsf(y1) < 1.f && fabsf(y2) < 1.f;
            float gx = (y0+1.f)*(0.5f*(SS-1));
            float gy = (y1+1.f)*(0.5f*(SS-1));
            float gz = (y2+1.f)*(0.5f*(SS-1));
            int x0  = min(max((int)floorf(gx), 0), SS-2);
            int y0i = min(max((int)floorf(gy), 0), SS-2);
            int z0  = min(max((int)floorf(gz), 0), SS-2);
            ffx[p] = gx-(float)x0; ffy[p] = gy-(float)y0i; ffz[p] = gz-(float)z0;
            idx[p] = z0*(SS*SS) + y0i*SS + x0;
            wv[p] = samp ? 1.f : 0.f;
        }

        if (TR) {
            const float4* tb = tw + ((size_t)ku << 12);
            // two pixel-pairs: issue 16 gathers, lerp, next 16, lerp.
            // (compiler may hoist the second batch under the first wait)
            {
                float4 C0[8], C1[8];
                GATHER8(C0, tb + idx[0]);
                GATHER8(C1, tb + idx[1]);
                TRILERP_ACC(0, C0);
                TRILERP_ACC(1, C1);
            }
            {
                float4 C2[8], C3[8];
                GATHER8(C2, tb + idx[2]);
                GATHER8(C3, tb + idx[3]);
                TRILERP_ACC(2, C2);
                TRILERP_ACC(3, C3);
            }
        } else {
            const float* tp = tpl + (size_t)ku * (4 * S3);
#pragma unroll
            for (int p = 0; p < GPIX; ++p) {
                float sv[4];
#pragma unroll
                for (int c = 0; c < 4; ++c) {
                    const float* tc = tp + c * S3;
                    int id = idx[p];
                    float c000 = tc[id],              c001 = tc[id+1];
                    float c010 = tc[id+SS],           c011 = tc[id+SS+1];
                    float c100 = tc[id+SS*SS],        c101 = tc[id+SS*SS+1];
                    float c110 = tc[id+SS*SS+SS],     c111 = tc[id+SS*SS+SS+1];
                    float c00 = c000*(1.f-ffx[p]) + c001*ffx[p];
                    float c01 = c010*(1.f-ffx[p]) + c011*ffx[p];
                    float c10 = c100*(1.f-ffx[p]) + c101*ffx[p];
                    float c11 = c110*(1.f-ffx[p]) + c111*ffx[p];
                    sv[c] = (c00*(1.f-ffy[p]) + c01*ffy[p])*(1.f-ffz[p])
                          + (c10*(1.f-ffy[p]) + c11*ffy[p])*ffz[p];
                }
                sv0[p] += sv[0]*wv[p]; sv1[p] += sv[1]*wv[p];
                sv2[p] += sv[2]*wv[p]; sv3[p] += sv[3]*wv[p];
            }
        }
    }

#pragma unroll
    for (int p = 0; p < GPIX; ++p) {
        float alpha = tvalid[p] ? sv3[p] * dtn : 0.f;
        float A = wave_incl_scan(alpha);               // inclusive prefix of alpha
        float Aex = __shfl_up(A, 1, 64);
        if (lane == 0) Aex = 0.f;
        // alpha>=0 => accA=min(prefix,1); contrib identical to reference recurrence
        float contrib = fminf(Aex + alpha, 1.f) - fminf(Aex, 1.f);
        float cr = wave_incl_scan(sv0[p] * contrib);   // lane63 = total
        float cg = wave_incl_scan(sv1[p] * contrib);
        float cb = wave_incl_scan(sv2[p] * contrib);
        float At = fminf(A, 1.f);
        if (lane == 63) {
            const int pix = pixidx[p];
            out[0*HH*WW + pix] = cr;
            out[1*HH*WW + pix] = cg;
            out[2*HH*WW + pix] = cb;
            out[3*HH*WW + pix] = At;
            const int b1 = 4*HH*WW;
            out[b1 + pix*3+0] = vx + rx[p]*tmn[p];
            out[b1 + pix*3+1] = vy + ry[p]*tmn[p];
            out[b1 + pix*3+2] = vz + rz[p]*tmn[p];
            const int b2 = b1 + HH*WW*3;
            out[b2 + pix*3+0] = vx + rx[p]*tmx[p];
            out[b2 + pix*3+1] = vy + ry[p]*tmx[p];
            out[b2 + pix*3+2] = vz + rz[p]*tmx[p];
        }
    }
}

extern "C" void kernel_launch(void* const* d_in, const int* in_sizes, int n_in,
                              void* d_out, int out_size, void* d_ws, size_t ws_size,
                              hipStream_t stream) {
    const float* viewpos   = (const float*)d_in[0];
    // d_in[1] = viewrot, unused by the reference
    const float* raydir    = (const float*)d_in[2];
    const float* tpl       = (const float*)d_in[3];
    const float* primpos   = (const float*)d_in[4];
    const float* primrot   = (const float*)d_in[5];
    const float* primscale = (const float*)d_in[6];
    const float* dtp       = (const float*)d_in[7];
    float* out = (float*)d_out;

    const size_t twbytes = (size_t)KK * S3 * 4 * sizeof(float);  // 4 MiB
    const int nwaves = (HH * WW) / GPIX;                          // 4096
    dim3 block(256), grid(nwaves * 64 / 256);                     // 1024 blocks

    if (ws_size >= twbytes) {
        transpose_tpl<<<dim3((KK * S3 + 255) / 256), block, 0, stream>>>(tpl, (float4*)d_ws);
        raymarch_kernel<true><<<grid, block, 0, stream>>>(
            viewpos, raydir, tpl, primpos, primrot, primscale, dtp,
            (const float4*)d_ws, out);
    } else {
        raymarch_kernel<false><<<grid, block, 0, stream>>>(
            viewpos, raydir, tpl, primpos, primrot, primscale, dtp,
            (const float4*)d_ws, out);
    }
}

// Round 5
// 45.831 us; speedup vs baseline: 1.1879x; 1.1879x over previous
//
#include <hip/hip_runtime.h>

#define HH 128
#define WW 128
#define KK 64
#define SS 16
#define S3 (SS * SS * SS)
#define VOLRADIUS 256.0f
#define CULL_EPS 1e-3f

// ---- DPP inclusive scan (gfx9 pattern: row_shr 1/2/4/8 + row_bcast 15/31) ----
template <int CTRL, int RM>
__device__ __forceinline__ float dpp_add(float x) {
    int y = __builtin_amdgcn_update_dpp(0, __float_as_int(x), CTRL, RM, 0xF, false);
    return x + __int_as_float(y);
}
__device__ __forceinline__ float wave_incl_scan(float x) {
    x = dpp_add<0x111, 0xF>(x);   // row_shr:1
    x = dpp_add<0x112, 0xF>(x);   // row_shr:2
    x = dpp_add<0x114, 0xF>(x);   // row_shr:4
    x = dpp_add<0x118, 0xF>(x);   // row_shr:8
    x = dpp_add<0x142, 0xA>(x);   // row_bcast:15 -> rows 1,3
    x = dpp_add<0x143, 0xC>(x);   // row_bcast:31 -> rows 2,3
    return x;                     // lane i = sum(lanes 0..i); lane 63 = total
}

#define LERP4(a, b, f) make_float4(a.x*(1.f-(f)) + b.x*(f), a.y*(1.f-(f)) + b.y*(f), \
                                   a.z*(1.f-(f)) + b.z*(f), a.w*(1.f-(f)) + b.w*(f))

// template [K,4,S,S,S] -> ws [K,S,S,S,4] so each trilinear corner is one float4
__global__ __launch_bounds__(256) void transpose_tpl(const float* __restrict__ tpl,
                                                     float4* __restrict__ tw) {
    int i = blockIdx.x * blockDim.x + threadIdx.x;      // 0 .. K*S3
    if (i >= KK * S3) return;
    int k = i >> 12, v = i & (S3 - 1);
    const float* src = tpl + ((size_t)k * 4 * S3) + v;
    tw[i] = make_float4(src[0], src[S3], src[2 * S3], src[3 * S3]);
}

template <bool TR>
__global__ __launch_bounds__(256, 6) void raymarch_kernel(
    const float* __restrict__ viewpos,   // [3]
    const float* __restrict__ raydir,    // [H,W,3]
    const float* __restrict__ tpl,       // [K,4,S,S,S]
    const float* __restrict__ primpos,   // [K,3]
    const float* __restrict__ primrot,   // [K,3,3]
    const float* __restrict__ primscale, // [K,3]
    const float* __restrict__ dtp,       // [1]
    const float4* __restrict__ tw,       // [K,S3] rgba (if TR)
    float* __restrict__ out)
{
    const int lane = threadIdx.x & 63;
    const int pix  = (int)((blockIdx.x * blockDim.x + threadIdx.x) >> 6);
    if (pix >= HH * WW) return;

    const float vx = viewpos[0] / VOLRADIUS;
    const float vy = viewpos[1] / VOLRADIUS;
    const float vz = viewpos[2] / VOLRADIUS;
    const float dtn = dtp[0] / VOLRADIUS;

    const float Rx = raydir[pix*3+0], Ry = raydir[pix*3+1], Rz = raydir[pix*3+2];

    // slab vs [-1,1]^3, exactly as reference
    float t1x = (-1.f-vx)/Rx, t2x = (1.f-vx)/Rx;
    float t1y = (-1.f-vy)/Ry, t2y = (1.f-vy)/Ry;
    float t1z = (-1.f-vz)/Rz, t2z = (1.f-vz)/Rz;
    float tmin = fmaxf(fminf(t1x,t2x), fmaxf(fminf(t1y,t2y), fminf(t1z,t2z)));
    float tmax = fminf(fmaxf(t1x,t2x), fminf(fmaxf(t1y,t2y), fmaxf(t1z,t2z)));
    bool inter = tmin < tmax;
    float tmin_ = inter ? tmin : 0.f;
    float tmax_ = inter ? tmax : 0.f;
    float t0 = fmaxf(tmin_, 0.f);
    float t = t0 + (float)lane * dtn;              // lane = step index
    const bool tvalid = t < tmax_;
    const float posx = vx + Rx*t;
    const float posy = vy + Ry*t;
    const float posz = vz + Rz*t;

    // ---- cull phase: lane = prim k, conservative ray-vs-OBB in local space ----
    unsigned long long mask;
    {
        const float px = primpos[lane*3+0], py = primpos[lane*3+1], pz = primpos[lane*3+2];
        const float r00 = primrot[lane*9+0], r01 = primrot[lane*9+1], r02 = primrot[lane*9+2];
        const float r10 = primrot[lane*9+3], r11 = primrot[lane*9+4], r12 = primrot[lane*9+5];
        const float r20 = primrot[lane*9+6], r21 = primrot[lane*9+7], r22 = primrot[lane*9+8];
        const float sx = primscale[lane*3+0], sy = primscale[lane*3+1], sz = primscale[lane*3+2];
        float bb[3], dd[3];
        bb[0] = ((vx-px)*r00 + (vy-py)*r10 + (vz-pz)*r20) * sx;
        bb[1] = ((vx-px)*r01 + (vy-py)*r11 + (vz-pz)*r21) * sy;
        bb[2] = ((vx-px)*r02 + (vy-py)*r12 + (vz-pz)*r22) * sz;
        dd[0] = (Rx*r00 + Ry*r10 + Rz*r20) * sx;
        dd[1] = (Rx*r01 + Ry*r11 + Rz*r21) * sy;
        dd[2] = (Rx*r02 + Ry*r12 + Rz*r22) * sz;
        float tend = fminf(tmax_, t0 + 63.f*dtn);
        float te = t0, tx = tend;
#pragma unroll
        for (int j = 0; j < 3; ++j) {
            float ta, tb2;
            if (fabsf(dd[j]) > 1e-12f) {
                float inv = 1.f / dd[j];
                ta  = (-1.f - CULL_EPS - bb[j]) * inv;
                tb2 = ( 1.f + CULL_EPS - bb[j]) * inv;
            } else {
                bool ok = fabsf(bb[j]) <= 1.f + CULL_EPS;
                ta  = ok ? -3e38f :  3e38f;
                tb2 = ok ?  3e38f : -3e38f;
            }
            te = fmaxf(te, fminf(ta, tb2));
            tx = fminf(tx, fmaxf(ta, tb2));
        }
        mask = __ballot(te <= tx);
    }

    float sv0 = 0.f, sv1 = 0.f, sv2 = 0.f, sv3 = 0.f;

    while (mask) {
        const int ku = __builtin_amdgcn_readfirstlane(__ffsll(mask) - 1);
        mask &= mask - 1;
        // wave-uniform index -> scalar (s_load) param reads
        const float qpx = primpos[ku*3+0], qpy = primpos[ku*3+1], qpz = primpos[ku*3+2];
        const float q00 = primrot[ku*9+0], q01 = primrot[ku*9+1], q02 = primrot[ku*9+2];
        const float q10 = primrot[ku*9+3], q11 = primrot[ku*9+4], q12 = primrot[ku*9+5];
        const float q20 = primrot[ku*9+6], q21 = primrot[ku*9+7], q22 = primrot[ku*9+8];
        const float qsx = primscale[ku*3+0], qsy = primscale[ku*3+1], qsz = primscale[ku*3+2];

        // branchless: reference gathers with clamped idx for every (point,prim)
        // and multiplies by `inside` -- identical math for inside lanes, exact +0 else.
        float xmx = posx-qpx, xmy = posy-qpy, xmz = posz-qpz;
        float y0 = (xmx*q00 + xmy*q10 + xmz*q20) * qsx;
        float y1 = (xmx*q01 + xmy*q11 + xmz*q21) * qsy;
        float y2 = (xmx*q02 + xmy*q12 + xmz*q22) * qsz;
        bool samp = tvalid && fabsf(y0) < 1.f && fabsf(y1) < 1.f && fabsf(y2) < 1.f;
        float gx = (y0+1.f)*(0.5f*(SS-1));
        float gy = (y1+1.f)*(0.5f*(SS-1));
        float gz = (y2+1.f)*(0.5f*(SS-1));
        int x0  = min(max((int)floorf(gx), 0), SS-2);
        int y0i = min(max((int)floorf(gy), 0), SS-2);
        int z0  = min(max((int)floorf(gz), 0), SS-2);
        float fx = gx-(float)x0, fy = gy-(float)y0i, fz = gz-(float)z0;
        int idx = z0*(SS*SS) + y0i*SS + x0;
        float w = samp ? 1.f : 0.f;

        if (TR) {
            const float4* tb = tw + ((size_t)ku << 12) + idx;
            float4 c000 = tb[0],          c001 = tb[1];
            float4 c010 = tb[SS],         c011 = tb[SS+1];
            float4 c100 = tb[SS*SS],      c101 = tb[SS*SS+1];
            float4 c110 = tb[SS*SS+SS],   c111 = tb[SS*SS+SS+1];
            float4 c00 = LERP4(c000, c001, fx);
            float4 c01 = LERP4(c010, c011, fx);
            float4 c10 = LERP4(c100, c101, fx);
            float4 c11 = LERP4(c110, c111, fx);
            float4 e0  = LERP4(c00, c01, fy);
            float4 e1  = LERP4(c10, c11, fy);
            sv0 += (e0.x*(1.f-fz) + e1.x*fz) * w;
            sv1 += (e0.y*(1.f-fz) + e1.y*fz) * w;
            sv2 += (e0.z*(1.f-fz) + e1.z*fz) * w;
            sv3 += (e0.w*(1.f-fz) + e1.w*fz) * w;
        } else {
            const float* tp = tpl + (size_t)ku * (4 * S3);
            float sv[4];
#pragma unroll
            for (int c = 0; c < 4; ++c) {
                const float* tc = tp + c * S3;
                float c000 = tc[idx],              c001 = tc[idx+1];
                float c010 = tc[idx+SS],           c011 = tc[idx+SS+1];
                float c100 = tc[idx+SS*SS],        c101 = tc[idx+SS*SS+1];
                float c110 = tc[idx+SS*SS+SS],     c111 = tc[idx+SS*SS+SS+1];
                float c00 = c000*(1.f-fx) + c001*fx;
                float c01 = c010*(1.f-fx) + c011*fx;
                float c10 = c100*(1.f-fx) + c101*fx;
                float c11 = c110*(1.f-fx) + c111*fx;
                sv[c] = (c00*(1.f-fy) + c01*fy)*(1.f-fz)
                      + (c10*(1.f-fy) + c11*fy)*fz;
            }
            sv0 += sv[0]*w; sv1 += sv[1]*w; sv2 += sv[2]*w; sv3 += sv[3]*w;
        }
    }

    // ---- compositing in closed form: alpha >= 0 => accA = min(prefix,1) ----
    float alpha = tvalid ? sv3 * dtn : 0.f;
    float A = wave_incl_scan(alpha);               // inclusive prefix of alpha
    float Aex = __shfl_up(A, 1, 64);
    if (lane == 0) Aex = 0.f;
    float contrib = fminf(Aex + alpha, 1.f) - fminf(Aex, 1.f);
    float cr = wave_incl_scan(sv0 * contrib);      // lane63 = total
    float cg = wave_incl_scan(sv1 * contrib);
    float cb = wave_incl_scan(sv2 * contrib);
    float At = fminf(A, 1.f);

    if (lane == 63) {
        out[0*HH*WW + pix] = cr;
        out[1*HH*WW + pix] = cg;
        out[2*HH*WW + pix] = cb;
        out[3*HH*WW + pix] = At;
        const int b1 = 4*HH*WW;
        out[b1 + pix*3+0] = vx + Rx*tmin_;
        out[b1 + pix*3+1] = vy + Ry*tmin_;
        out[b1 + pix*3+2] = vz + Rz*tmin_;
        const int b2 = b1 + HH*WW*3;
        out[b2 + pix*3+0] = vx + Rx*tmax_;
        out[b2 + pix*3+1] = vy + Ry*tmax_;
        out[b2 + pix*3+2] = vz + Rz*tmax_;
    }
}

extern "C" void kernel_launch(void* const* d_in, const int* in_sizes, int n_in,
                              void* d_out, int out_size, void* d_ws, size_t ws_size,
                              hipStream_t stream) {
    const float* viewpos   = (const float*)d_in[0];
    // d_in[1] = viewrot, unused by the reference
    const float* raydir    = (const float*)d_in[2];
    const float* tpl       = (const float*)d_in[3];
    const float* primpos   = (const float*)d_in[4];
    const float* primrot   = (const float*)d_in[5];
    const float* primscale = (const float*)d_in[6];
    const float* dtp       = (const float*)d_in[7];
    float* out = (float*)d_out;

    const size_t twbytes = (size_t)KK * S3 * 4 * sizeof(float);  // 4 MiB
    dim3 block(256), grid(HH * WW * 64 / 256);                    // 4096 blocks

    if (ws_size >= twbytes) {
        transpose_tpl<<<dim3((KK * S3 + 255) / 256), block, 0, stream>>>(tpl, (float4*)d_ws);
        raymarch_kernel<true><<<grid, block, 0, stream>>>(
            viewpos, raydir, tpl, primpos, primrot, primscale, dtp,
            (const float4*)d_ws, out);
    } else {
        raymarch_kernel<false><<<grid, block, 0, stream>>>(
            viewpos, raydir, tpl, primpos, primrot, primscale, dtp,
            (const float4*)d_ws, out);
    }
}

// Round 6
// 36.057 us; speedup vs baseline: 1.5099x; 1.2711x over previous
//
#include <hip/hip_runtime.h>

#define HH 128
#define WW 128
#define KK 64
#define SS 16
#define S3 (SS * SS * SS)
#define VOLRADIUS 256.0f
#define CULL_EPS 1e-3f

// ---- DPP inclusive scan (gfx9 pattern: row_shr 1/2/4/8 + row_bcast 15/31) ----
template <int CTRL, int RM>
__device__ __forceinline__ float dpp_add(float x) {
    int y = __builtin_amdgcn_update_dpp(0, __float_as_int(x), CTRL, RM, 0xF, false);
    return x + __int_as_float(y);
}
__device__ __forceinline__ float wave_incl_scan(float x) {
    x = dpp_add<0x111, 0xF>(x);   // row_shr:1
    x = dpp_add<0x112, 0xF>(x);   // row_shr:2
    x = dpp_add<0x114, 0xF>(x);   // row_shr:4
    x = dpp_add<0x118, 0xF>(x);   // row_shr:8
    x = dpp_add<0x142, 0xA>(x);   // row_bcast:15 -> rows 1,3
    x = dpp_add<0x143, 0xC>(x);   // row_bcast:31 -> rows 2,3
    return x;                     // lane i = sum(lanes 0..i); lane 63 = total
}

#define LERP4(a, b, f) make_float4(a.x*(1.f-(f)) + b.x*(f), a.y*(1.f-(f)) + b.y*(f), \
                                   a.z*(1.f-(f)) + b.z*(f), a.w*(1.f-(f)) + b.w*(f))

// template [K,4,S,S,S] -> ws [K,S,S,S,4] so each trilinear corner is one float4
__global__ __launch_bounds__(256) void transpose_tpl(const float* __restrict__ tpl,
                                                     float4* __restrict__ tw) {
    int i = blockIdx.x * blockDim.x + threadIdx.x;      // 0 .. K*S3
    if (i >= KK * S3) return;
    int k = i >> 12, v = i & (S3 - 1);
    const float* src = tpl + ((size_t)k * 4 * S3) + v;
    tw[i] = make_float4(src[0], src[S3], src[2 * S3], src[3 * S3]);
}

template <bool TR>
__global__ __launch_bounds__(256, 6) void raymarch_kernel(
    const float* __restrict__ viewpos,   // [3]
    const float* __restrict__ raydir,    // [H,W,3]
    const float* __restrict__ tpl,       // [K,4,S,S,S]
    const float* __restrict__ primpos,   // [K,3]
    const float* __restrict__ primrot,   // [K,3,3]
    const float* __restrict__ primscale, // [K,3]
    const float* __restrict__ dtp,       // [1]
    const float4* __restrict__ tw,       // [K,S3] rgba (if TR)
    float* __restrict__ out)
{
    const int lane = threadIdx.x & 63;
    const int pix  = (int)((blockIdx.x * blockDim.x + threadIdx.x) >> 6);
    if (pix >= HH * WW) return;

    const float vx = viewpos[0] / VOLRADIUS;
    const float vy = viewpos[1] / VOLRADIUS;
    const float vz = viewpos[2] / VOLRADIUS;
    const float dtn = dtp[0] / VOLRADIUS;

    const float Rx = raydir[pix*3+0], Ry = raydir[pix*3+1], Rz = raydir[pix*3+2];

    // slab vs [-1,1]^3, exactly as reference
    float t1x = (-1.f-vx)/Rx, t2x = (1.f-vx)/Rx;
    float t1y = (-1.f-vy)/Ry, t2y = (1.f-vy)/Ry;
    float t1z = (-1.f-vz)/Rz, t2z = (1.f-vz)/Rz;
    float tmin = fmaxf(fminf(t1x,t2x), fmaxf(fminf(t1y,t2y), fminf(t1z,t2z)));
    float tmax = fminf(fmaxf(t1x,t2x), fminf(fmaxf(t1y,t2y), fmaxf(t1z,t2z)));
    bool inter = tmin < tmax;
    float tmin_ = inter ? tmin : 0.f;
    float tmax_ = inter ? tmax : 0.f;
    float t0 = fmaxf(tmin_, 0.f);
    float t = t0 + (float)lane * dtn;              // lane = step index
    const bool tvalid = t < tmax_;
    const float posx = vx + Rx*t;
    const float posy = vy + Ry*t;
    const float posz = vz + Rz*t;

    // ---- cull phase: lane = prim k, conservative ray-vs-OBB in local space ----
    unsigned long long mask;
    {
        const float px = primpos[lane*3+0], py = primpos[lane*3+1], pz = primpos[lane*3+2];
        const float r00 = primrot[lane*9+0], r01 = primrot[lane*9+1], r02 = primrot[lane*9+2];
        const float r10 = primrot[lane*9+3], r11 = primrot[lane*9+4], r12 = primrot[lane*9+5];
        const float r20 = primrot[lane*9+6], r21 = primrot[lane*9+7], r22 = primrot[lane*9+8];
        const float sx = primscale[lane*3+0], sy = primscale[lane*3+1], sz = primscale[lane*3+2];
        float bb[3], dd[3];
        bb[0] = ((vx-px)*r00 + (vy-py)*r10 + (vz-pz)*r20) * sx;
        bb[1] = ((vx-px)*r01 + (vy-py)*r11 + (vz-pz)*r21) * sy;
        bb[2] = ((vx-px)*r02 + (vy-py)*r12 + (vz-pz)*r22) * sz;
        dd[0] = (Rx*r00 + Ry*r10 + Rz*r20) * sx;
        dd[1] = (Rx*r01 + Ry*r11 + Rz*r21) * sy;
        dd[2] = (Rx*r02 + Ry*r12 + Rz*r22) * sz;
        float tend = fminf(tmax_, t0 + 63.f*dtn);
        float te = t0, tx = tend;
#pragma unroll
        for (int j = 0; j < 3; ++j) {
            float ta, tb2;
            if (fabsf(dd[j]) > 1e-12f) {
                float inv = 1.f / dd[j];
                ta  = (-1.f - CULL_EPS - bb[j]) * inv;
                tb2 = ( 1.f + CULL_EPS - bb[j]) * inv;
            } else {
                bool ok = fabsf(bb[j]) <= 1.f + CULL_EPS;
                ta  = ok ? -3e38f :  3e38f;
                tb2 = ok ?  3e38f : -3e38f;
            }
            te = fmaxf(te, fminf(ta, tb2));
            tx = fminf(tx, fmaxf(ta, tb2));
        }
        mask = __ballot(te <= tx);
    }

    float sv0 = 0.f, sv1 = 0.f, sv2 = 0.f, sv3 = 0.f;

    while (mask) {
        const int ku = __builtin_amdgcn_readfirstlane(__ffsll(mask) - 1);
        mask &= mask - 1;
        // wave-uniform index -> scalar (s_load) param reads
        const float qpx = primpos[ku*3+0], qpy = primpos[ku*3+1], qpz = primpos[ku*3+2];
        const float q00 = primrot[ku*9+0], q01 = primrot[ku*9+1], q02 = primrot[ku*9+2];
        const float q10 = primrot[ku*9+3], q11 = primrot[ku*9+4], q12 = primrot[ku*9+5];
        const float q20 = primrot[ku*9+6], q21 = primrot[ku*9+7], q22 = primrot[ku*9+8];
        const float qsx = primscale[ku*3+0], qsy = primscale[ku*3+1], qsz = primscale[ku*3+2];

        float xmx = posx-qpx, xmy = posy-qpy, xmz = posz-qpz;
        float y0 = (xmx*q00 + xmy*q10 + xmz*q20) * qsx;
        float y1 = (xmx*q01 + xmy*q11 + xmz*q21) * qsy;
        float y2 = (xmx*q02 + xmy*q12 + xmz*q22) * qsz;
        bool samp = tvalid && fabsf(y0) < 1.f && fabsf(y1) < 1.f && fabsf(y2) < 1.f;

        // exec-masked sampling: outside lanes issue NO memory transactions,
        // and contribute exactly 0 (identical to reference's inside-multiply).
        if (samp) {
            float gx = (y0+1.f)*(0.5f*(SS-1));
            float gy = (y1+1.f)*(0.5f*(SS-1));
            float gz = (y2+1.f)*(0.5f*(SS-1));
            int x0  = min(max((int)floorf(gx), 0), SS-2);
            int y0i = min(max((int)floorf(gy), 0), SS-2);
            int z0  = min(max((int)floorf(gz), 0), SS-2);
            float fx = gx-(float)x0, fy = gy-(float)y0i, fz = gz-(float)z0;
            int idx = z0*(SS*SS) + y0i*SS + x0;

            if (TR) {
                const float4* tb = tw + ((size_t)ku << 12) + idx;
                float4 c000 = tb[0],          c001 = tb[1];
                float4 c010 = tb[SS],         c011 = tb[SS+1];
                float4 c100 = tb[SS*SS],      c101 = tb[SS*SS+1];
                float4 c110 = tb[SS*SS+SS],   c111 = tb[SS*SS+SS+1];
                float4 c00 = LERP4(c000, c001, fx);
                float4 c01 = LERP4(c010, c011, fx);
                float4 c10 = LERP4(c100, c101, fx);
                float4 c11 = LERP4(c110, c111, fx);
                float4 e0  = LERP4(c00, c01, fy);
                float4 e1  = LERP4(c10, c11, fy);
                sv0 += e0.x*(1.f-fz) + e1.x*fz;
                sv1 += e0.y*(1.f-fz) + e1.y*fz;
                sv2 += e0.z*(1.f-fz) + e1.z*fz;
                sv3 += e0.w*(1.f-fz) + e1.w*fz;
            } else {
                const float* tp = tpl + (size_t)ku * (4 * S3);
                float sv[4];
#pragma unroll
                for (int c = 0; c < 4; ++c) {
                    const float* tc = tp + c * S3;
                    float c000 = tc[idx],              c001 = tc[idx+1];
                    float c010 = tc[idx+SS],           c011 = tc[idx+SS+1];
                    float c100 = tc[idx+SS*SS],        c101 = tc[idx+SS*SS+1];
                    float c110 = tc[idx+SS*SS+SS],     c111 = tc[idx+SS*SS+SS+1];
                    float c00 = c000*(1.f-fx) + c001*fx;
                    float c01 = c010*(1.f-fx) + c011*fx;
                    float c10 = c100*(1.f-fx) + c101*fx;
                    float c11 = c110*(1.f-fx) + c111*fx;
                    sv[c] = (c00*(1.f-fy) + c01*fy)*(1.f-fz)
                          + (c10*(1.f-fy) + c11*fy)*fz;
                }
                sv0 += sv[0]; sv1 += sv[1]; sv2 += sv[2]; sv3 += sv[3];
            }
        }
    }

    // ---- compositing in closed form: alpha >= 0 => accA = min(prefix,1) ----
    float alpha = tvalid ? sv3 * dtn : 0.f;
    float A = wave_incl_scan(alpha);               // inclusive prefix of alpha
    float Aex = __shfl_up(A, 1, 64);
    if (lane == 0) Aex = 0.f;
    float contrib = fminf(Aex + alpha, 1.f) - fminf(Aex, 1.f);
    float cr = wave_incl_scan(sv0 * contrib);      // lane63 = total
    float cg = wave_incl_scan(sv1 * contrib);
    float cb = wave_incl_scan(sv2 * contrib);
    float At = fminf(A, 1.f);

    if (lane == 63) {
        out[0*HH*WW + pix] = cr;
        out[1*HH*WW + pix] = cg;
        out[2*HH*WW + pix] = cb;
        out[3*HH*WW + pix] = At;
        const int b1 = 4*HH*WW;
        out[b1 + pix*3+0] = vx + Rx*tmin_;
        out[b1 + pix*3+1] = vy + Ry*tmin_;
        out[b1 + pix*3+2] = vz + Rz*tmin_;
        const int b2 = b1 + HH*WW*3;
        out[b2 + pix*3+0] = vx + Rx*tmax_;
        out[b2 + pix*3+1] = vy + Ry*tmax_;
        out[b2 + pix*3+2] = vz + Rz*tmax_;
    }
}

extern "C" void kernel_launch(void* const* d_in, const int* in_sizes, int n_in,
                              void* d_out, int out_size, void* d_ws, size_t ws_size,
                              hipStream_t stream) {
    const float* viewpos   = (const float*)d_in[0];
    // d_in[1] = viewrot, unused by the reference
    const float* raydir    = (const float*)d_in[2];
    const float* tpl       = (const float*)d_in[3];
    const float* primpos   = (const float*)d_in[4];
    const float* primrot   = (const float*)d_in[5];
    const float* primscale = (const float*)d_in[6];
    const float* dtp       = (const float*)d_in[7];
    float* out = (float*)d_out;

    const size_t twbytes = (size_t)KK * S3 * 4 * sizeof(float);  // 4 MiB
    dim3 block(256), grid(HH * WW * 64 / 256);                    // 4096 blocks

    if (ws_size >= twbytes) {
        transpose_tpl<<<dim3((KK * S3 + 255) / 256), block, 0, stream>>>(tpl, (float4*)d_ws);
        raymarch_kernel<true><<<grid, block, 0, stream>>>(
            viewpos, raydir, tpl, primpos, primrot, primscale, dtp,
            (const float4*)d_ws, out);
    } else {
        raymarch_kernel<false><<<grid, block, 0, stream>>>(
            viewpos, raydir, tpl, primpos, primrot, primscale, dtp,
            (const float4*)d_ws, out);
    }
}